// Round 1
// baseline (4883.529 us; speedup 1.0000x reference)
//
#include <hip/hip_runtime.h>
#include <cstdint>
#include <cstddef>

// Problem sizes (fixed)
#define B_ 16
#define S_ 256
#define V_ 32000
#define D_ 512
#define H_ 512
#define T_ 50
#define KX (T_ + D_)        // 562  input width
#define G4 (4 * H_)         // 2048 gate width
#define M_ (B_ * S_)        // 4096 rows

__device__ __forceinline__ float sigmoidf_(float x) { return 1.f / (1.f + expf(-x)); }

// ---------------------------------------------------------------------------
// Generic fp32 tiled GEMM: C[M,N] = A[M,K] @ B[K,N] + bias[N]
// BM=BN=128, BK=16, 256 threads, 8x8 micro-tile.
// Requires M % 128 == 0, N % 128 == 0 (true here); K guarded.
// ---------------------------------------------------------------------------
#define BM 128
#define BN 128
#define BK 16

__global__ __launch_bounds__(256) void gemm_bias(
    const float* __restrict__ A, const float* __restrict__ B,
    const float* __restrict__ bias, float* __restrict__ C,
    int M, int N, int K) {
  __shared__ float As[BK][BM];
  __shared__ float Bs[BK][BN];
  const int tid = threadIdx.x;
  const int bm = blockIdx.y * BM;
  const int bn = blockIdx.x * BN;
  const int tx = tid & 15;
  const int ty = tid >> 4;
  float acc[8][8] = {};

  for (int k0 = 0; k0 < K; k0 += BK) {
    // A tile: 128 rows x 16 k. thread t -> row t>>1, k-half (t&1)*8
    {
      int r = tid >> 1;
      int kk = (tid & 1) * 8;
      const float* Ap = A + (size_t)(bm + r) * K + k0 + kk;
      #pragma unroll
      for (int i = 0; i < 8; ++i) {
        int kg = k0 + kk + i;
        As[kk + i][r] = (kg < K) ? Ap[i] : 0.f;
      }
    }
    // B tile: 16 k x 128 n. thread t -> k t>>4, n (t&15)*8
    {
      int kk = tid >> 4;
      int nn = (tid & 15) * 8;
      int kg = k0 + kk;
      const float* Bp = B + (size_t)kg * N + bn + nn;
      #pragma unroll
      for (int i = 0; i < 8; ++i)
        Bs[kk][nn + i] = (kg < K) ? Bp[i] : 0.f;
    }
    __syncthreads();
    #pragma unroll
    for (int k = 0; k < BK; ++k) {
      float a[8], bv[8];
      #pragma unroll
      for (int i = 0; i < 8; ++i) a[i] = As[k][ty * 8 + i];
      #pragma unroll
      for (int i = 0; i < 8; ++i) bv[i] = Bs[k][tx * 8 + i];
      #pragma unroll
      for (int i = 0; i < 8; ++i)
        #pragma unroll
        for (int j = 0; j < 8; ++j)
          acc[i][j] += a[i] * bv[j];
    }
    __syncthreads();
  }

  #pragma unroll
  for (int i = 0; i < 8; ++i) {
    int m = bm + ty * 8 + i;
    float* Cp = C + (size_t)m * N + bn + tx * 8;
    #pragma unroll
    for (int j = 0; j < 8; ++j)
      Cp[j] = acc[i][j] + bias[bn + tx * 8 + j];
  }
}

// ---------------------------------------------------------------------------
// Input projection: xs_proj[m][g] = concat(topic[m], emb[tok[m]])[k] @ Wx[k][g] + bias[g]
// Same structure as gemm_bias but A is gathered on the fly. M=4096,N=2048,K=562.
// ---------------------------------------------------------------------------
__global__ __launch_bounds__(256) void proj_gemm(
    const int* __restrict__ tokens, const float* __restrict__ topic,
    const float* __restrict__ embed, const float* __restrict__ Wx,
    const float* __restrict__ bias, float* __restrict__ out) {
  __shared__ float As[BK][BM];
  __shared__ float Bs[BK][BN];
  const int tid = threadIdx.x;
  const int bm = blockIdx.y * BM;
  const int bn = blockIdx.x * BN;
  const int tx = tid & 15;
  const int ty = tid >> 4;
  float acc[8][8] = {};

  for (int k0 = 0; k0 < KX; k0 += BK) {
    {
      int r = tid >> 1;
      int kk = (tid & 1) * 8;
      int m = bm + r;
      int tok = tokens[m];
      #pragma unroll
      for (int i = 0; i < 8; ++i) {
        int kg = k0 + kk + i;
        float v = 0.f;
        if (kg < T_)       v = topic[(size_t)m * T_ + kg];
        else if (kg < KX)  v = embed[(size_t)tok * D_ + (kg - T_)];
        As[kk + i][r] = v;
      }
    }
    {
      int kk = tid >> 4;
      int nn = (tid & 15) * 8;
      int kg = k0 + kk;
      const float* Bp = Wx + (size_t)kg * G4 + bn + nn;
      #pragma unroll
      for (int i = 0; i < 8; ++i)
        Bs[kk][nn + i] = (kg < KX) ? Bp[i] : 0.f;
    }
    __syncthreads();
    #pragma unroll
    for (int k = 0; k < BK; ++k) {
      float a[8], bv[8];
      #pragma unroll
      for (int i = 0; i < 8; ++i) a[i] = As[k][ty * 8 + i];
      #pragma unroll
      for (int i = 0; i < 8; ++i) bv[i] = Bs[k][tx * 8 + i];
      #pragma unroll
      for (int i = 0; i < 8; ++i)
        #pragma unroll
        for (int j = 0; j < 8; ++j)
          acc[i][j] += a[i] * bv[j];
    }
    __syncthreads();
  }

  #pragma unroll
  for (int i = 0; i < 8; ++i) {
    int m = bm + ty * 8 + i;
    float* Cp = out + (size_t)m * G4 + bn + tx * 8;
    #pragma unroll
    for (int j = 0; j < 8; ++j)
      Cp[j] = acc[i][j] + bias[bn + tx * 8 + j];
  }
}

// ---------------------------------------------------------------------------
// One LSTM step. grid (H/64, B), 256 threads.
// z[b][g] = xs_proj[b,s][g] + sum_k h_prev[b][k] * Wh[k][g]
// i,j,f,o = split(z, 4); c = sig(f)*c + sig(i)*tanh(j); h = sig(o)*tanh(c)
// h_prev read from hs_all row s-1 (zeros at s==0); h written to row s.
// c read/written per (b,u) by the same thread -> no cross-block hazard.
// ---------------------------------------------------------------------------
__global__ __launch_bounds__(256) void lstm_step(
    const float* __restrict__ xs_proj, const float* __restrict__ Wh,
    float* __restrict__ hs_all, float* __restrict__ c_state, int s) {
  const int ub = blockIdx.x * 64;
  const int b  = blockIdx.y;
  const int tid = threadIdx.x;
  const int ul = tid & 63;
  const int kc = tid >> 6;   // 0..3, k-chunk of 128
  const int u  = ub + ul;

  __shared__ float h_lds[H_];
  __shared__ float part[4][4][64];

  if (s > 0) {
    const float* hprev = hs_all + ((size_t)b * S_ + (s - 1)) * H_;
    for (int i = tid; i < H_; i += 256) h_lds[i] = hprev[i];
  } else {
    for (int i = tid; i < H_; i += 256) h_lds[i] = 0.f;
  }
  __syncthreads();

  float a0 = 0.f, a1 = 0.f, a2 = 0.f, a3 = 0.f;
  const float* W = Wh + (size_t)(kc * 128) * G4 + u;
  const float* hp = h_lds + kc * 128;
  #pragma unroll 4
  for (int k = 0; k < 128; ++k) {
    float hv = hp[k];
    const float* w = W + (size_t)k * G4;
    a0 += hv * w[0];
    a1 += hv * w[512];
    a2 += hv * w[1024];
    a3 += hv * w[1536];
  }
  part[kc][0][ul] = a0;
  part[kc][1][ul] = a1;
  part[kc][2][ul] = a2;
  part[kc][3][ul] = a3;
  __syncthreads();

  if (tid < 64) {
    int uu = ub + tid;
    size_t row = (size_t)b * S_ + s;
    const float* zp = xs_proj + row * G4;
    float zi = zp[uu]          + part[0][0][tid] + part[1][0][tid] + part[2][0][tid] + part[3][0][tid];
    float zj = zp[uu + 512]    + part[0][1][tid] + part[1][1][tid] + part[2][1][tid] + part[3][1][tid];
    float zf = zp[uu + 1024]   + part[0][2][tid] + part[1][2][tid] + part[2][2][tid] + part[3][2][tid];
    float zo = zp[uu + 1536]   + part[0][3][tid] + part[1][3][tid] + part[2][3][tid] + part[3][3][tid];

    float c = (s == 0) ? 0.f : c_state[b * H_ + uu];
    c = sigmoidf_(zf) * c + sigmoidf_(zi) * tanhf(zj);
    float h = sigmoidf_(zo) * tanhf(c);
    c_state[b * H_ + uu] = c;
    hs_all[row * H_ + uu] = h;
  }
}

// ---------------------------------------------------------------------------
extern "C" void kernel_launch(void* const* d_in, const int* in_sizes, int n_in,
                              void* d_out, int out_size, void* d_ws, size_t ws_size,
                              hipStream_t stream) {
  const int*   tokens = (const int*)  d_in[0];
  const float* topic  = (const float*)d_in[1];
  const float* embed  = (const float*)d_in[2];
  const float* lk     = (const float*)d_in[3];   // [1074, 2048]
  const float* lb     = (const float*)d_in[4];   // [2048]
  const float* dw     = (const float*)d_in[5];   // [512, 32000]
  const float* db     = (const float*)d_in[6];   // [32000]
  float* out = (float*)d_out;                    // [4096, 32000]

  float* xs_proj = (float*)d_ws;                         // M_ x G4   (33.5 MB)
  float* hs_all  = xs_proj + (size_t)M_ * G4;            // M_ x H_   (8.4 MB)
  float* c_state = hs_all + (size_t)M_ * H_;             // B_ x H_   (32 KB)

  // 1. input projection for all (b,s), bias folded in
  hipLaunchKernelGGL(proj_gemm, dim3(G4 / BN, M_ / BM), dim3(256), 0, stream,
                     tokens, topic, embed, lk, lb, xs_proj);

  // 2. sequential LSTM steps (recurrent part only)
  const float* Wh = lk + (size_t)KX * G4;  // rows 562..1073
  for (int s = 0; s < S_; ++s) {
    hipLaunchKernelGGL(lstm_step, dim3(H_ / 64, B_), dim3(256), 0, stream,
                       xs_proj, Wh, hs_all, c_state, s);
  }

  // 3. dense logits GEMM
  hipLaunchKernelGGL(gemm_bias, dim3(V_ / BN, M_ / BM), dim3(256), 0, stream,
                     hs_all, dw, db, out, M_, V_, H_);
}

// Round 2
// 3283.986 us; speedup vs baseline: 1.4871x; 1.4871x over previous
//
#include <hip/hip_runtime.h>
#include <cstdint>
#include <cstddef>

// Problem sizes (fixed)
#define B_ 16
#define S_ 256
#define V_ 32000
#define D_ 512
#define H_ 512
#define T_ 50
#define KX (T_ + D_)        // 562  input width
#define G4 (4 * H_)         // 2048 gate width
#define M_ (B_ * S_)        // 4096 rows

typedef unsigned short u16;
typedef unsigned int u32;
typedef __attribute__((ext_vector_type(8))) short bf16x8;
typedef __attribute__((ext_vector_type(4))) float f32x4;
typedef __attribute__((ext_vector_type(4))) u16 u16x4;

__device__ __forceinline__ float sigmoidf_(float x) { return 1.f / (1.f + expf(-x)); }

__device__ __forceinline__ u16 f2bf_rne(float x) {
  u32 u = __float_as_uint(x);
  u32 r = (u + 0x7fffu + ((u >> 16) & 1u)) >> 16;
  return (u16)r;
}
__device__ __forceinline__ float bf2f(u16 h) { return __uint_as_float(((u32)h) << 16); }

#define GLD_LDS16(g, l) __builtin_amdgcn_global_load_lds( \
    (const __attribute__((address_space(1))) void*)(g), \
    (__attribute__((address_space(3))) void*)(l), 16, 0, 0)

// ---------------------------------------------------------------------------
// fp32 tiled GEMM (fallback path only): C[M,N] = A[M,K] @ B[K,N] + bias[N]
// ---------------------------------------------------------------------------
#define BM 128
#define BN 128
#define BK 16

__global__ __launch_bounds__(256) void gemm_bias(
    const float* __restrict__ A, const float* __restrict__ B,
    const float* __restrict__ bias, float* __restrict__ C,
    int M, int N, int K) {
  __shared__ float As[BK][BM];
  __shared__ float Bs[BK][BN];
  const int tid = threadIdx.x;
  const int bm = blockIdx.y * BM;
  const int bn = blockIdx.x * BN;
  const int tx = tid & 15;
  const int ty = tid >> 4;
  float acc[8][8] = {};

  for (int k0 = 0; k0 < K; k0 += BK) {
    {
      int r = tid >> 1;
      int kk = (tid & 1) * 8;
      const float* Ap = A + (size_t)(bm + r) * K + k0 + kk;
      #pragma unroll
      for (int i = 0; i < 8; ++i) {
        int kg = k0 + kk + i;
        As[kk + i][r] = (kg < K) ? Ap[i] : 0.f;
      }
    }
    {
      int kk = tid >> 4;
      int nn = (tid & 15) * 8;
      int kg = k0 + kk;
      const float* Bp = B + (size_t)kg * N + bn + nn;
      #pragma unroll
      for (int i = 0; i < 8; ++i)
        Bs[kk][nn + i] = (kg < K) ? Bp[i] : 0.f;
    }
    __syncthreads();
    #pragma unroll
    for (int k = 0; k < BK; ++k) {
      float a[8], bv[8];
      #pragma unroll
      for (int i = 0; i < 8; ++i) a[i] = As[k][ty * 8 + i];
      #pragma unroll
      for (int i = 0; i < 8; ++i) bv[i] = Bs[k][tx * 8 + i];
      #pragma unroll
      for (int i = 0; i < 8; ++i)
        #pragma unroll
        for (int j = 0; j < 8; ++j)
          acc[i][j] += a[i] * bv[j];
    }
    __syncthreads();
  }

  #pragma unroll
  for (int i = 0; i < 8; ++i) {
    int m = bm + ty * 8 + i;
    float* Cp = C + (size_t)m * N + bn + tx * 8;
    #pragma unroll
    for (int j = 0; j < 8; ++j)
      Cp[j] = acc[i][j] + bias[bn + tx * 8 + j];
  }
}

// ---------------------------------------------------------------------------
// Input projection GEMM (fp32, unchanged this round)
// ---------------------------------------------------------------------------
__global__ __launch_bounds__(256) void proj_gemm(
    const int* __restrict__ tokens, const float* __restrict__ topic,
    const float* __restrict__ embed, const float* __restrict__ Wx,
    const float* __restrict__ bias, float* __restrict__ out) {
  __shared__ float As[BK][BM];
  __shared__ float Bs[BK][BN];
  const int tid = threadIdx.x;
  const int bm = blockIdx.y * BM;
  const int bn = blockIdx.x * BN;
  const int tx = tid & 15;
  const int ty = tid >> 4;
  float acc[8][8] = {};

  for (int k0 = 0; k0 < KX; k0 += BK) {
    {
      int r = tid >> 1;
      int kk = (tid & 1) * 8;
      int m = bm + r;
      int tok = tokens[m];
      #pragma unroll
      for (int i = 0; i < 8; ++i) {
        int kg = k0 + kk + i;
        float v = 0.f;
        if (kg < T_)       v = topic[(size_t)m * T_ + kg];
        else if (kg < KX)  v = embed[(size_t)tok * D_ + (kg - T_)];
        As[kk + i][r] = v;
      }
    }
    {
      int kk = tid >> 4;
      int nn = (tid & 15) * 8;
      int kg = k0 + kk;
      const float* Bp = Wx + (size_t)kg * G4 + bn + nn;
      #pragma unroll
      for (int i = 0; i < 8; ++i)
        Bs[kk][nn + i] = (kg < KX) ? Bp[i] : 0.f;
    }
    __syncthreads();
    #pragma unroll
    for (int k = 0; k < BK; ++k) {
      float a[8], bv[8];
      #pragma unroll
      for (int i = 0; i < 8; ++i) a[i] = As[k][ty * 8 + i];
      #pragma unroll
      for (int i = 0; i < 8; ++i) bv[i] = Bs[k][tx * 8 + i];
      #pragma unroll
      for (int i = 0; i < 8; ++i)
        #pragma unroll
        for (int j = 0; j < 8; ++j)
          acc[i][j] += a[i] * bv[j];
    }
    __syncthreads();
  }

  #pragma unroll
  for (int i = 0; i < 8; ++i) {
    int m = bm + ty * 8 + i;
    float* Cp = out + (size_t)m * G4 + bn + tx * 8;
    #pragma unroll
    for (int j = 0; j < 8; ++j)
      Cp[j] = acc[i][j] + bias[bn + tx * 8 + j];
  }
}

// ---------------------------------------------------------------------------
// One LSTM step (unchanged this round)
// ---------------------------------------------------------------------------
__global__ __launch_bounds__(256) void lstm_step(
    const float* __restrict__ xs_proj, const float* __restrict__ Wh,
    float* __restrict__ hs_all, float* __restrict__ c_state, int s) {
  const int ub = blockIdx.x * 64;
  const int b  = blockIdx.y;
  const int tid = threadIdx.x;
  const int ul = tid & 63;
  const int kc = tid >> 6;
  const int u  = ub + ul;

  __shared__ float h_lds[H_];
  __shared__ float part[4][4][64];

  if (s > 0) {
    const float* hprev = hs_all + ((size_t)b * S_ + (s - 1)) * H_;
    for (int i = tid; i < H_; i += 256) h_lds[i] = hprev[i];
  } else {
    for (int i = tid; i < H_; i += 256) h_lds[i] = 0.f;
  }
  __syncthreads();

  float a0 = 0.f, a1 = 0.f, a2 = 0.f, a3 = 0.f;
  const float* W = Wh + (size_t)(kc * 128) * G4 + u;
  const float* hp = h_lds + kc * 128;
  #pragma unroll 4
  for (int k = 0; k < 128; ++k) {
    float hv = hp[k];
    const float* w = W + (size_t)k * G4;
    a0 += hv * w[0];
    a1 += hv * w[512];
    a2 += hv * w[1024];
    a3 += hv * w[1536];
  }
  part[kc][0][ul] = a0;
  part[kc][1][ul] = a1;
  part[kc][2][ul] = a2;
  part[kc][3][ul] = a3;
  __syncthreads();

  if (tid < 64) {
    int uu = ub + tid;
    size_t row = (size_t)b * S_ + s;
    const float* zp = xs_proj + row * G4;
    float zi = zp[uu]          + part[0][0][tid] + part[1][0][tid] + part[2][0][tid] + part[3][0][tid];
    float zj = zp[uu + 512]    + part[0][1][tid] + part[1][1][tid] + part[2][1][tid] + part[3][1][tid];
    float zf = zp[uu + 1024]   + part[0][2][tid] + part[1][2][tid] + part[2][2][tid] + part[3][2][tid];
    float zo = zp[uu + 1536]   + part[0][3][tid] + part[1][3][tid] + part[2][3][tid] + part[3][3][tid];

    float c = (s == 0) ? 0.f : c_state[b * H_ + uu];
    c = sigmoidf_(zf) * c + sigmoidf_(zi) * tanhf(zj);
    float h = sigmoidf_(zo) * tanhf(c);
    c_state[b * H_ + uu] = c;
    hs_all[row * H_ + uu] = h;
  }
}

// ---------------------------------------------------------------------------
// Split dense_w [512][V] fp32 -> Whi/Wlo [V][512] bf16 (transposed, split)
// grid (V/32, 512/32), block 256
// ---------------------------------------------------------------------------
__global__ __launch_bounds__(256) void split_w_t(
    const float* __restrict__ W, u16* __restrict__ Whi, u16* __restrict__ Wlo) {
  __shared__ float tile[32][33];
  const int n0 = blockIdx.x * 32, k0 = blockIdx.y * 32;
  const int r = threadIdx.x >> 3;
  const int c4 = (threadIdx.x & 7) * 4;
  const float* src = W + (size_t)(k0 + r) * V_ + n0 + c4;
  #pragma unroll
  for (int i = 0; i < 4; ++i) tile[r][c4 + i] = src[i];
  __syncthreads();
  u16x4 hv, lv;
  #pragma unroll
  for (int i = 0; i < 4; ++i) {
    float x = tile[c4 + i][r];
    u16 h = f2bf_rne(x);
    hv[i] = h;
    lv[i] = f2bf_rne(x - bf2f(h));
  }
  size_t o = (size_t)(n0 + r) * 512 + k0 + c4;
  *(u16x4*)(Whi + o) = hv;
  *(u16x4*)(Wlo + o) = lv;
}

// ---------------------------------------------------------------------------
// Split hs_all fp32 -> Ahi/Alo bf16 (same layout). n = M_*512, float4 per thread.
// ---------------------------------------------------------------------------
__global__ __launch_bounds__(256) void split_a(
    const float* __restrict__ A, u16* __restrict__ Ahi, u16* __restrict__ Alo) {
  size_t i = ((size_t)blockIdx.x * 256 + threadIdx.x) * 4;
  float4 v = *(const float4*)(A + i);
  u16x4 hv, lv;
  float xs[4] = {v.x, v.y, v.z, v.w};
  #pragma unroll
  for (int j = 0; j < 4; ++j) {
    u16 h = f2bf_rne(xs[j]);
    hv[j] = h;
    lv[j] = f2bf_rne(xs[j] - bf2f(h));
  }
  *(u16x4*)(Ahi + i) = hv;
  *(u16x4*)(Alo + i) = lv;
}

// ---------------------------------------------------------------------------
// Split-bf16 MFMA GEMM: C[M_][V_] = A[M_][512] @ W^T[V_][512]^T + bias
// A given as Ahi/Alo [M][512] bf16, W as Whi/Wlo [V][512] bf16 (K-contiguous).
// 128x128 tile, BK=32, 4 waves, m97-style global_load_lds staging.
// ---------------------------------------------------------------------------
__global__ __launch_bounds__(256) void gemm_split_mfma(
    const u16* __restrict__ Ahi, const u16* __restrict__ Alo,
    const u16* __restrict__ Bhi, const u16* __restrict__ Blo,
    const float* __restrict__ bias, float* __restrict__ C) {
  __shared__ u16 lds[4][128 * 32];
  const int tid = threadIdx.x;
  const int w = tid >> 6, lane = tid & 63;
  const int bm = blockIdx.y * 128;
  const int bn = blockIdx.x * 128;
  const int wm = (w >> 1) * 64, wn = (w & 1) * 64;

  f32x4 zero = {0.f, 0.f, 0.f, 0.f};
  f32x4 acc[4][4];
  #pragma unroll
  for (int m = 0; m < 4; ++m)
    #pragma unroll
    for (int n = 0; n < 4; ++n) acc[m][n] = zero;

  const u16* src0 = Ahi + (size_t)bm * 512;
  const u16* src1 = Alo + (size_t)bm * 512;
  const u16* src2 = Bhi + (size_t)bn * 512;
  const u16* src3 = Blo + (size_t)bn * 512;

  const int lrow = lane >> 2;          // 0..15 within chunk
  const int lkb  = (lane & 3) * 8;     // k offset (bf16 units) within row
  const int kb   = (lane >> 4) * 8;    // fragment k offset

  for (int k0 = 0; k0 < 512; k0 += 32) {
    // stage 4 buffers; wave w stages chunks {2w, 2w+1} of each (16 rows/chunk)
    #pragma unroll
    for (int cc = 0; cc < 2; ++cc) {
      const int c = w * 2 + cc;
      const int row = c * 16 + lrow;
      const size_t goff = (size_t)row * 512 + k0 + lkb;
      u16* l = &lds[0][0] + c * 16 * 32;
      GLD_LDS16(src0 + goff, l);
      GLD_LDS16(src1 + goff, l + 128 * 32);
      GLD_LDS16(src2 + goff, l + 2 * 128 * 32);
      GLD_LDS16(src3 + goff, l + 3 * 128 * 32);
    }
    __syncthreads();

    bf16x8 ah[4], al[4], bh[4], bl[4];
    #pragma unroll
    for (int m = 0; m < 4; ++m) {
      int r = wm + m * 16 + (lane & 15);
      ah[m] = *(const bf16x8*)&lds[0][r * 32 + kb];
      al[m] = *(const bf16x8*)&lds[1][r * 32 + kb];
    }
    #pragma unroll
    for (int n = 0; n < 4; ++n) {
      int r = wn + n * 16 + (lane & 15);
      bh[n] = *(const bf16x8*)&lds[2][r * 32 + kb];
      bl[n] = *(const bf16x8*)&lds[3][r * 32 + kb];
    }
    #pragma unroll
    for (int m = 0; m < 4; ++m)
      #pragma unroll
      for (int n = 0; n < 4; ++n) {
        acc[m][n] = __builtin_amdgcn_mfma_f32_16x16x32_bf16(al[m], bh[n], acc[m][n], 0, 0, 0);
        acc[m][n] = __builtin_amdgcn_mfma_f32_16x16x32_bf16(ah[m], bl[n], acc[m][n], 0, 0, 0);
        acc[m][n] = __builtin_amdgcn_mfma_f32_16x16x32_bf16(ah[m], bh[n], acc[m][n], 0, 0, 0);
      }
    __syncthreads();
  }

  const int lc = lane & 15, lr4 = (lane >> 4) * 4;
  #pragma unroll
  for (int n = 0; n < 4; ++n) {
    int col = bn + wn + n * 16 + lc;
    float bv = bias[col];
    #pragma unroll
    for (int m = 0; m < 4; ++m) {
      int row0 = bm + wm + m * 16 + lr4;
      float* Cp = C + (size_t)row0 * V_ + col;
      #pragma unroll
      for (int j = 0; j < 4; ++j)
        Cp[(size_t)j * V_] = acc[m][n][j] + bv;
    }
  }
}

// ---------------------------------------------------------------------------
extern "C" void kernel_launch(void* const* d_in, const int* in_sizes, int n_in,
                              void* d_out, int out_size, void* d_ws, size_t ws_size,
                              hipStream_t stream) {
  const int*   tokens = (const int*)  d_in[0];
  const float* topic  = (const float*)d_in[1];
  const float* embed  = (const float*)d_in[2];
  const float* lk     = (const float*)d_in[3];   // [1074, 2048]
  const float* lb     = (const float*)d_in[4];   // [2048]
  const float* dw     = (const float*)d_in[5];   // [512, 32000]
  const float* db     = (const float*)d_in[6];   // [32000]
  float* out = (float*)d_out;                    // [4096, 32000]

  // workspace layout (all 256B-aligned by construction)
  char* ws = (char*)d_ws;
  float* xs_proj = (float*)ws;                              // 33,554,432 B
  float* hs_all  = (float*)(ws + 33554432);                 //  8,388,608 B
  float* c_state = (float*)(ws + 33554432 + 8388608);       //     32,768 B
  size_t off = 33554432 + 8388608 + 32768;
  u16* Ahi = (u16*)(ws + off);            off += (size_t)M_ * 512 * 2;   // 4 MB
  u16* Alo = (u16*)(ws + off);            off += (size_t)M_ * 512 * 2;   // 4 MB
  u16* Whi = (u16*)(ws + off);            off += (size_t)V_ * 512 * 2;   // 32.8 MB
  u16* Wlo = (u16*)(ws + off);            off += (size_t)V_ * 512 * 2;   // 32.8 MB
  const bool use_mfma = (ws_size >= off);

  // 1. W split+transpose (independent of everything else)
  if (use_mfma) {
    hipLaunchKernelGGL(split_w_t, dim3(V_ / 32, 512 / 32), dim3(256), 0, stream,
                       dw, Whi, Wlo);
  }

  // 2. input projection
  hipLaunchKernelGGL(proj_gemm, dim3(G4 / BN, M_ / BM), dim3(256), 0, stream,
                     tokens, topic, embed, lk, lb, xs_proj);

  // 3. sequential LSTM
  const float* Wh = lk + (size_t)KX * G4;
  for (int s = 0; s < S_; ++s) {
    hipLaunchKernelGGL(lstm_step, dim3(H_ / 64, B_), dim3(256), 0, stream,
                       xs_proj, Wh, hs_all, c_state, s);
  }

  // 4. dense logits GEMM
  if (use_mfma) {
    hipLaunchKernelGGL(split_a, dim3((M_ * 512) / (256 * 4)), dim3(256), 0, stream,
                       hs_all, Ahi, Alo);
    hipLaunchKernelGGL(gemm_split_mfma, dim3(V_ / 128, M_ / 128), dim3(256), 0, stream,
                       Ahi, Alo, Whi, Wlo, db, out);
  } else {
    hipLaunchKernelGGL(gemm_bias, dim3(V_ / BN, M_ / BM), dim3(256), 0, stream,
                       hs_all, dw, db, out, M_, V_, H_);
  }
}

// Round 3
// 2310.868 us; speedup vs baseline: 2.1133x; 1.4211x over previous
//
#include <hip/hip_runtime.h>
#include <cstdint>
#include <cstddef>

// Problem sizes (fixed)
#define B_ 16
#define S_ 256
#define V_ 32000
#define D_ 512
#define H_ 512
#define T_ 50
#define KX (T_ + D_)        // 562  input width
#define G4 (4 * H_)         // 2048 gate width
#define M_ (B_ * S_)        // 4096 rows

#define GBLK 64             // persistent LSTM blocks (1 per CU, <=256 CUs)
#define UPB 8               // h-units per block
#define WST 520             // padded LDS K-stride in u16 (16B-aligned, ~2-way banks)

typedef unsigned short u16;
typedef unsigned int u32;
typedef __attribute__((ext_vector_type(8))) short bf16x8;
typedef __attribute__((ext_vector_type(4))) float f32x4;
typedef __attribute__((ext_vector_type(4))) u16 u16x4;
typedef __attribute__((ext_vector_type(8))) u16 u16x8;

__device__ __forceinline__ float sigmoidf_(float x) { return 1.f / (1.f + expf(-x)); }

__device__ __forceinline__ u16 f2bf_rne(float x) {
  u32 u = __float_as_uint(x);
  u32 r = (u + 0x7fffu + ((u >> 16) & 1u)) >> 16;
  return (u16)r;
}
__device__ __forceinline__ float bf2f(u16 h) { return __uint_as_float(((u32)h) << 16); }

#define GLD_LDS16(g, l) __builtin_amdgcn_global_load_lds( \
    (const __attribute__((address_space(1))) void*)(g), \
    (__attribute__((address_space(3))) void*)(l), 16, 0, 0)

// ---------------------------------------------------------------------------
// Input projection GEMM (fp32): xs_proj = concat(topic, emb[tok]) @ Wx + bias
// ---------------------------------------------------------------------------
#define BM 128
#define BN 128
#define BK 16

__global__ __launch_bounds__(256) void proj_gemm(
    const int* __restrict__ tokens, const float* __restrict__ topic,
    const float* __restrict__ embed, const float* __restrict__ Wx,
    const float* __restrict__ bias, float* __restrict__ out) {
  __shared__ float As[BK][BM];
  __shared__ float Bs[BK][BN];
  const int tid = threadIdx.x;
  const int bm = blockIdx.y * BM;
  const int bn = blockIdx.x * BN;
  const int tx = tid & 15;
  const int ty = tid >> 4;
  float acc[8][8] = {};

  for (int k0 = 0; k0 < KX; k0 += BK) {
    {
      int r = tid >> 1;
      int kk = (tid & 1) * 8;
      int m = bm + r;
      int tok = tokens[m];
      #pragma unroll
      for (int i = 0; i < 8; ++i) {
        int kg = k0 + kk + i;
        float v = 0.f;
        if (kg < T_)       v = topic[(size_t)m * T_ + kg];
        else if (kg < KX)  v = embed[(size_t)tok * D_ + (kg - T_)];
        As[kk + i][r] = v;
      }
    }
    {
      int kk = tid >> 4;
      int nn = (tid & 15) * 8;
      int kg = k0 + kk;
      const float* Bp = Wx + (size_t)kg * G4 + bn + nn;
      #pragma unroll
      for (int i = 0; i < 8; ++i)
        Bs[kk][nn + i] = (kg < KX) ? Bp[i] : 0.f;
    }
    __syncthreads();
    #pragma unroll
    for (int k = 0; k < BK; ++k) {
      float a[8], bv[8];
      #pragma unroll
      for (int i = 0; i < 8; ++i) a[i] = As[k][ty * 8 + i];
      #pragma unroll
      for (int i = 0; i < 8; ++i) bv[i] = Bs[k][tx * 8 + i];
      #pragma unroll
      for (int i = 0; i < 8; ++i)
        #pragma unroll
        for (int j = 0; j < 8; ++j)
          acc[i][j] += a[i] * bv[j];
    }
    __syncthreads();
  }

  #pragma unroll
  for (int i = 0; i < 8; ++i) {
    int m = bm + ty * 8 + i;
    float* Cp = out + (size_t)m * G4 + bn + tx * 8;
    #pragma unroll
    for (int j = 0; j < 8; ++j)
      Cp[j] = acc[i][j] + bias[bn + tx * 8 + j];
  }
}

// ---------------------------------------------------------------------------
// Persistent LSTM. GBLK blocks, 256 threads. Block g owns h-units
// [g*8, g*8+8) for ALL 16 batches; weight slice (32 gate cols x 512 K)
// lives split-bf16 in LDS for all 256 steps. Hand-rolled device barrier
// between steps (monotonic counter in ws). h double-buffered in global as
// bf16 hi/lo; h also written directly to Ahi/Alo rows for the logits GEMM.
// ---------------------------------------------------------------------------
__global__ __launch_bounds__(256, 1) void lstm_persist(
    const float* __restrict__ xs_proj, const float* __restrict__ Wh,
    u16* __restrict__ hhi, u16* __restrict__ hlo,   // [2][16][512] each
    u16* __restrict__ Ahi, u16* __restrict__ Alo,   // [M_][512]
    u32* __restrict__ ctr) {
  __shared__ u16 whi_l[32 * WST];
  __shared__ u16 wlo_l[32 * WST];
  __shared__ u16 hhi_l[16 * WST];
  __shared__ u16 hlo_l[16 * WST];
  __shared__ float zpart[4][16][34];

  const int tid = threadIdx.x;
  const int w = tid >> 6;
  const int lane = tid & 63;
  const int u0 = blockIdx.x * UPB;

  // one-time weight slice preload: col c = q*8 + j  ->  global col q*512+u0+j
  for (int idx = tid; idx < 32 * 512; idx += 256) {
    int c = idx & 31, k = idx >> 5;
    int gc = (c >> 3) * 512 + u0 + (c & 7);
    float v = Wh[(size_t)k * G4 + gc];
    u16 hi = f2bf_rne(v);
    whi_l[c * WST + k] = hi;
    wlo_l[c * WST + k] = f2bf_rne(v - bf2f(hi));
  }

  float c_reg = 0.f;                    // cell state, valid on tid<128
  const int rb = tid >> 3;              // batch     (reduce threads)
  const int rj = tid & 7;               // unit off  (reduce threads)
  const int kb = (lane >> 4) * 8;       // fragment k offset
  const int l15 = lane & 15;

  for (int s = 0; s < S_; ++s) {
    const int par = s & 1;
    // ---- stage h_{s-1} (buffer `par`; zeros at s==0 via memset) ----
    {
      const u16* gh = hhi + par * 8192;
      const u16* gl = hlo + par * 8192;
      #pragma unroll
      for (int i = 0; i < 4; ++i) {
        int f = tid * 32 + i * 8;
        int row = f >> 9, col = f & 511;
        *(u16x8*)&hhi_l[row * WST + col] = *(const u16x8*)(gh + f);
        *(u16x8*)&hlo_l[row * WST + col] = *(const u16x8*)(gl + f);
      }
    }
    __syncthreads();

    // ---- MFMA: wave w handles K quarter [w*128, w*128+128) ----
    {
      f32x4 acc0 = {0.f, 0.f, 0.f, 0.f};
      f32x4 acc1 = {0.f, 0.f, 0.f, 0.f};
      #pragma unroll
      for (int ks = 0; ks < 4; ++ks) {
        const int k = w * 128 + ks * 32 + kb;
        bf16x8 ah  = *(const bf16x8*)&hhi_l[l15 * WST + k];
        bf16x8 al  = *(const bf16x8*)&hlo_l[l15 * WST + k];
        bf16x8 b0h = *(const bf16x8*)&whi_l[l15 * WST + k];
        bf16x8 b0l = *(const bf16x8*)&wlo_l[l15 * WST + k];
        bf16x8 b1h = *(const bf16x8*)&whi_l[(16 + l15) * WST + k];
        bf16x8 b1l = *(const bf16x8*)&wlo_l[(16 + l15) * WST + k];
        acc0 = __builtin_amdgcn_mfma_f32_16x16x32_bf16(al, b0h, acc0, 0, 0, 0);
        acc0 = __builtin_amdgcn_mfma_f32_16x16x32_bf16(ah, b0l, acc0, 0, 0, 0);
        acc0 = __builtin_amdgcn_mfma_f32_16x16x32_bf16(ah, b0h, acc0, 0, 0, 0);
        acc1 = __builtin_amdgcn_mfma_f32_16x16x32_bf16(al, b1h, acc1, 0, 0, 0);
        acc1 = __builtin_amdgcn_mfma_f32_16x16x32_bf16(ah, b1l, acc1, 0, 0, 0);
        acc1 = __builtin_amdgcn_mfma_f32_16x16x32_bf16(ah, b1h, acc1, 0, 0, 0);
      }
      #pragma unroll
      for (int jj = 0; jj < 4; ++jj) {
        int r = (lane >> 4) * 4 + jj;   // batch row (verified C/D layout)
        zpart[w][r][l15] = acc0[jj];
        zpart[w][r][16 + l15] = acc1[jj];
      }
    }
    __syncthreads();

    // ---- reduce across waves + gates + h write ----
    if (tid < 128) {
      const float* zp = xs_proj + ((size_t)rb * S_ + s) * G4 + u0 + rj;
      float zi = zp[0], zj2 = zp[512], zf = zp[1024], zo = zp[1536];
      #pragma unroll
      for (int ww = 0; ww < 4; ++ww) {
        zi  += zpart[ww][rb][rj];
        zj2 += zpart[ww][rb][8 + rj];
        zf  += zpart[ww][rb][16 + rj];
        zo  += zpart[ww][rb][24 + rj];
      }
      float cc = sigmoidf_(zf) * c_reg + sigmoidf_(zi) * tanhf(zj2);
      c_reg = cc;
      float h = sigmoidf_(zo) * tanhf(cc);
      u16 hh = f2bf_rne(h);
      u16 hl = f2bf_rne(h - bf2f(hh));
      const int np = (s + 1) & 1;
      const int hoff = rb * 512 + u0 + rj;
      hhi[np * 8192 + hoff] = hh;
      hlo[np * 8192 + hoff] = hl;
      const size_t ar = ((size_t)rb * S_ + s) * 512 + u0 + rj;
      Ahi[ar] = hh;
      Alo[ar] = hl;
    }
    __syncthreads();   // drain all global writes (vmcnt0) before arrive

    // ---- device-wide barrier (skip after last step) ----
    if (s != S_ - 1) {
      if (tid == 0) {
        __hip_atomic_fetch_add(ctr, 1u, __ATOMIC_ACQ_REL, __HIP_MEMORY_SCOPE_AGENT);
        const u32 target = (u32)GBLK * (u32)(s + 1);
        while (__hip_atomic_load(ctr, __ATOMIC_ACQUIRE, __HIP_MEMORY_SCOPE_AGENT) < target)
          __builtin_amdgcn_s_sleep(2);
      }
      __syncthreads();
    }
  }
}

// ---------------------------------------------------------------------------
// Split dense_w [512][V] fp32 -> Whi/Wlo [V][512] bf16 (transposed, split)
// ---------------------------------------------------------------------------
__global__ __launch_bounds__(256) void split_w_t(
    const float* __restrict__ W, u16* __restrict__ Whi, u16* __restrict__ Wlo) {
  __shared__ float tile[32][33];
  const int n0 = blockIdx.x * 32, k0 = blockIdx.y * 32;
  const int r = threadIdx.x >> 3;
  const int c4 = (threadIdx.x & 7) * 4;
  const float* src = W + (size_t)(k0 + r) * V_ + n0 + c4;
  #pragma unroll
  for (int i = 0; i < 4; ++i) tile[r][c4 + i] = src[i];
  __syncthreads();
  u16x4 hv, lv;
  #pragma unroll
  for (int i = 0; i < 4; ++i) {
    float x = tile[c4 + i][r];
    u16 h = f2bf_rne(x);
    hv[i] = h;
    lv[i] = f2bf_rne(x - bf2f(h));
  }
  size_t o = (size_t)(n0 + r) * 512 + k0 + c4;
  *(u16x4*)(Whi + o) = hv;
  *(u16x4*)(Wlo + o) = lv;
}

// ---------------------------------------------------------------------------
// Split-bf16 MFMA GEMM: C[M_][V_] = A[M_][512] @ W^T + bias (validated r1)
// ---------------------------------------------------------------------------
__global__ __launch_bounds__(256) void gemm_split_mfma(
    const u16* __restrict__ Ahi, const u16* __restrict__ Alo,
    const u16* __restrict__ Bhi, const u16* __restrict__ Blo,
    const float* __restrict__ bias, float* __restrict__ C) {
  __shared__ u16 lds[4][128 * 32];
  const int tid = threadIdx.x;
  const int w = tid >> 6, lane = tid & 63;
  const int bm = blockIdx.y * 128;
  const int bn = blockIdx.x * 128;
  const int wm = (w >> 1) * 64, wn = (w & 1) * 64;

  f32x4 zero = {0.f, 0.f, 0.f, 0.f};
  f32x4 acc[4][4];
  #pragma unroll
  for (int m = 0; m < 4; ++m)
    #pragma unroll
    for (int n = 0; n < 4; ++n) acc[m][n] = zero;

  const u16* src0 = Ahi + (size_t)bm * 512;
  const u16* src1 = Alo + (size_t)bm * 512;
  const u16* src2 = Bhi + (size_t)bn * 512;
  const u16* src3 = Blo + (size_t)bn * 512;

  const int lrow = lane >> 2;
  const int lkb  = (lane & 3) * 8;
  const int kb   = (lane >> 4) * 8;

  for (int k0 = 0; k0 < 512; k0 += 32) {
    #pragma unroll
    for (int cc = 0; cc < 2; ++cc) {
      const int c = w * 2 + cc;
      const int row = c * 16 + lrow;
      const size_t goff = (size_t)row * 512 + k0 + lkb;
      u16* l = &lds[0][0] + c * 16 * 32;
      GLD_LDS16(src0 + goff, l);
      GLD_LDS16(src1 + goff, l + 128 * 32);
      GLD_LDS16(src2 + goff, l + 2 * 128 * 32);
      GLD_LDS16(src3 + goff, l + 3 * 128 * 32);
    }
    __syncthreads();

    bf16x8 ah[4], al[4], bh[4], bl[4];
    #pragma unroll
    for (int m = 0; m < 4; ++m) {
      int r = wm + m * 16 + (lane & 15);
      ah[m] = *(const bf16x8*)&lds[0][r * 32 + kb];
      al[m] = *(const bf16x8*)&lds[1][r * 32 + kb];
    }
    #pragma unroll
    for (int n = 0; n < 4; ++n) {
      int r = wn + n * 16 + (lane & 15);
      bh[n] = *(const bf16x8*)&lds[2][r * 32 + kb];
      bl[n] = *(const bf16x8*)&lds[3][r * 32 + kb];
    }
    #pragma unroll
    for (int m = 0; m < 4; ++m)
      #pragma unroll
      for (int n = 0; n < 4; ++n) {
        acc[m][n] = __builtin_amdgcn_mfma_f32_16x16x32_bf16(al[m], bh[n], acc[m][n], 0, 0, 0);
        acc[m][n] = __builtin_amdgcn_mfma_f32_16x16x32_bf16(ah[m], bl[n], acc[m][n], 0, 0, 0);
        acc[m][n] = __builtin_amdgcn_mfma_f32_16x16x32_bf16(ah[m], bh[n], acc[m][n], 0, 0, 0);
      }
    __syncthreads();
  }

  const int lc = lane & 15, lr4 = (lane >> 4) * 4;
  #pragma unroll
  for (int n = 0; n < 4; ++n) {
    int col = bn + wn + n * 16 + lc;
    float bv = bias[col];
    #pragma unroll
    for (int m = 0; m < 4; ++m) {
      int row0 = bm + wm + m * 16 + lr4;
      float* Cp = C + (size_t)row0 * V_ + col;
      #pragma unroll
      for (int j = 0; j < 4; ++j)
        Cp[(size_t)j * V_] = acc[m][n][j] + bv;
    }
  }
}

// ---------------------------------------------------------------------------
extern "C" void kernel_launch(void* const* d_in, const int* in_sizes, int n_in,
                              void* d_out, int out_size, void* d_ws, size_t ws_size,
                              hipStream_t stream) {
  const int*   tokens = (const int*)  d_in[0];
  const float* topic  = (const float*)d_in[1];
  const float* embed  = (const float*)d_in[2];
  const float* lk     = (const float*)d_in[3];   // [1074, 2048]
  const float* lb     = (const float*)d_in[4];   // [2048]
  const float* dw     = (const float*)d_in[5];   // [512, 32000]
  const float* db     = (const float*)d_in[6];   // [32000]
  float* out = (float*)d_out;                    // [4096, 32000]

  char* ws = (char*)d_ws;
  size_t off = 0;
  float* xs_proj = (float*)(ws + off); off += (size_t)M_ * G4 * 4;   // 33.5 MB
  u16* Ahi = (u16*)(ws + off); off += (size_t)M_ * 512 * 2;          //  4 MB
  u16* Alo = (u16*)(ws + off); off += (size_t)M_ * 512 * 2;          //  4 MB
  u16* Whi = (u16*)(ws + off); off += (size_t)V_ * 512 * 2;          // 32.8 MB
  u16* Wlo = (u16*)(ws + off); off += (size_t)V_ * 512 * 2;          // 32.8 MB
  u16* hhi = (u16*)(ws + off); off += 2 * 8192 * 2;                  // 32 KB
  u16* hlo = (u16*)(ws + off); off += 2 * 8192 * 2;                  // 32 KB
  u32* ctr = (u32*)(ws + off); off += 256;

  // zero the barrier counter and h double-buffers every call (replay-safe)
  hipMemsetAsync(hhi, 0, 2 * 8192 * 2, stream);
  hipMemsetAsync(hlo, 0, 2 * 8192 * 2, stream);
  hipMemsetAsync(ctr, 0, 256, stream);

  // 1. dense-W split+transpose (independent)
  hipLaunchKernelGGL(split_w_t, dim3(V_ / 32, 512 / 32), dim3(256), 0, stream,
                     dw, Whi, Wlo);

  // 2. input projection
  hipLaunchKernelGGL(proj_gemm, dim3(G4 / BN, M_ / BM), dim3(256), 0, stream,
                     tokens, topic, embed, lk, lb, xs_proj);

  // 3. persistent LSTM over all 256 steps
  const float* Wh = lk + (size_t)KX * G4;
  hipLaunchKernelGGL(lstm_persist, dim3(GBLK), dim3(256), 0, stream,
                     xs_proj, Wh, hhi, hlo, Ahi, Alo, ctr);

  // 4. dense logits GEMM (split-bf16 MFMA)
  hipLaunchKernelGGL(gemm_split_mfma, dim3(V_ / 128, M_ / 128), dim3(256), 0, stream,
                     Ahi, Alo, Whi, Wlo, db, out);
}